// Round 1
// baseline (324.111 us; speedup 1.0000x reference)
//
#include <hip/hip_runtime.h>

// PETP_Quadratic R4: 32x32x16 MFMA restructure.
//   A-row m = lane&31  ==> each lane owns ONE position; entire A-side
//   (k-slices + all broadcasts s_u, g_i[u]) comes from the lane's own
//   128-channel feature row, read as a few ds_read_b128 from pos-major LDS.
//   N=32 in a single MFMA (no nh split), K=16 per MFMA (2 per u-step).
//   Wave = 32 positions, block = 3 waves (192 thr) = 16 batches, grid 1024
//   -> 12 waves/CU (3/SIMD) vs previous 8/CU.
// Fallbacks if this round underperforms:
//   - VGPR spill (scratch traffic) -> __launch_bounds__(192,2)
//   - L2-bound (MfmaUtil<55, TCC high) -> cooperative LDS B-staging

typedef _Float16 half8  __attribute__((ext_vector_type(8)));
typedef float    f32x16 __attribute__((ext_vector_type(16)));

#define NORM 0.022097086912079608f   /* 1/(32*sqrt(2)) */
#define INV_SQRT3 0.5773502691896258f
#define STR 136                       /* feat row stride in halfwords (272B, 16B-aligned) */

// ---------------- prep: fragment-swizzled f16 weights for 32x32x16 ----------------
// B-frag layout (16x32, K x N): lane l holds B[k=(l>>5)*8+j][n=l&31], j=0..7.
// B1s: blocks of 512 half (1KB): bi = ((t*2+seg)*32+u)*2+kh, k-channel v = kh*16+(l>>5)*8+j
//   seg0: NORM*W0[u][v][n]   seg1: NORM*INV_SQRT3*W1[u][v][n]
// B2s: bi2 = (t*32+u)*2+kh: NORM*(W2[u][v][n]+W3[v][u][n])
__global__ void prep_kernel(const float* __restrict__ Wa, const float* __restrict__ Wb,
                            const float* __restrict__ Wc, const float* __restrict__ Wd,
                            _Float16* __restrict__ B1s, _Float16* __restrict__ B2s) {
    const float* Ws[4] = {Wa, Wb, Wc, Wd};
    int idx = blockIdx.x * 256 + threadIdx.x;
    if (idx < 262144) {
        int j    = idx & 7;
        int lane = (idx >> 3) & 63;
        int kh   = (idx >> 9) & 1;
        int u    = (idx >> 10) & 31;
        int seg  = (idx >> 15) & 1;
        int t    = idx >> 16;
        int n = lane & 31;
        int v = kh * 16 + (lane >> 5) * 8 + j;
        const float* W = Ws[t];
        float val;
        if (seg == 0) val = NORM * W[u * 1024 + v * 32 + n];
        else          val = NORM * INV_SQRT3 * W[32768 + u * 1024 + v * 32 + n];
        B1s[idx] = (_Float16)val;
    } else {
        int idx2 = idx - 262144;
        if (idx2 < 131072) {
            int j    = idx2 & 7;
            int lane = (idx2 >> 3) & 63;
            int kh   = (idx2 >> 9) & 1;
            int u    = (idx2 >> 10) & 31;
            int t    = idx2 >> 15;
            int n = lane & 31;
            int v = kh * 16 + (lane >> 5) * 8 + j;
            const float* W = Ws[t];
            float val = NORM * (W[2 * 32768 + u * 1024 + v * 32 + n] +
                                W[3 * 32768 + v * 1024 + u * 32 + n]);
            B2s[idx2] = (_Float16)val;
        }
    }
}

// ---------------- main kernel ----------------
// WG = 192 thr (3 waves) owns 16 batches = 96 positions; wave owns 32 (one M-tile).
// feat[pos][ch] pos-major: ch 0..31 = s, 32+i*32+u = v-component i channel u.
__launch_bounds__(192, 3)
__global__ void petp_main(const float* __restrict__ x,
                          const _Float16* __restrict__ B1s,
                          const _Float16* __restrict__ B2s,
                          float* __restrict__ y) {
    __shared__ _Float16 feat[96 * STR];   // 26,112 B

    const int tid  = threadIdx.x;
    const int wave = tid >> 6;
    const int lane = tid & 63;
    const int mw = lane & 31;   // A row (position in tile) AND C/D col n
    const int q8 = lane >> 5;   // k-half within a K=16 MFMA

    f32x16 acc_s;
    f32x16 acc_v[3];
#pragma unroll
    for (int r = 0; r < 16; ++r) {
        acc_s[r] = 0.f; acc_v[0][r] = 0.f; acc_v[1][r] = 0.f; acc_v[2][r] = 0.f;
    }

    const int wg = blockIdx.x;
    const float* xg = x + (size_t)wg * (96 * 128);

#pragma unroll 1
    for (int t = 0; t < 4; ++t) {
        __syncthreads();   // prior variant's readers done
        // ---- build variant-t features into pos-major LDS ----
#pragma unroll 1
        for (int it = 0; it < 11; ++it) {
            int item = it * 192 + tid;        // 16 batches x 128 channels
            if (item < 2048) {
                int b = item >> 7;
                int c = item & 127;
                const float* bp = xg + b * 768 + c;
                float v00 = bp[0],   v01 = bp[128], v02 = bp[256];
                float v10 = bp[384], v11 = bp[512], v12 = bp[640];
                float rs0 = v00 + v01 + v02, rs1 = v10 + v11 + v12;
                float cs0 = v00 + v10, cs1 = v01 + v11, cs2 = v02 + v12;
                float tot = rs0 + rs1;
                float xv[6] = {v00, v01, v02, v10, v11, v12};
                float rs[2] = {rs0, rs1};
                float cs[3] = {cs0, cs1, cs2};
                int row;
                if (c < 32) row = c;
                else { int cc = c - 32; row = 32 + (cc % 3) * 32 + (cc / 3); }
                _Float16* fp = feat + row;
#pragma unroll
                for (int p6 = 0; p6 < 6; ++p6) {
                    int i = p6 / 3, j = p6 % 3;
                    float xvv = xv[p6];
                    float f;
                    if      (t == 0) f = xvv;
                    else if (t == 1) f = (rs[i] - xvv) * 0.5f;
                    else if (t == 2) f = cs[j] - xvv;
                    else             f = (tot - rs[i] - cs[j] + xvv) * 0.5f;
                    fp[(b * 6 + p6) * STR] = (_Float16)f;
                }
            }
        }
        __syncthreads();

        // ---- per-lane A-side: everything from my own position's row ----
        const _Float16* frow = feat + (wave * 32 + mw) * STR;
        half8 sl_s[2];       // k-slices of s (kh)
        half8 sl_v[2][3];    // k-slices of v (kh, component)
#pragma unroll
        for (int kh = 0; kh < 2; ++kh) {
            sl_s[kh] = *(const half8*)(frow + kh * 16 + q8 * 8);
#pragma unroll
            for (int i = 0; i < 3; ++i)
                sl_v[kh][i] = *(const half8*)(frow + 32 + i * 32 + kh * 16 + q8 * 8);
        }
        const _Float16* B1t = B1s + t * 65536 + lane * 8;
        const _Float16* B2t = B2s + t * 32768 + lane * 8;

#pragma unroll 1
        for (int cku = 0; cku < 4; ++cku) {
            // broadcast chunks: 8 u-values each, register-resident
            half8 bcS  = *(const half8*)(frow + cku * 8);
            half8 bcG0 = *(const half8*)(frow + 32 + cku * 8);
            half8 bcG1 = *(const half8*)(frow + 64 + cku * 8);
            half8 bcG2 = *(const half8*)(frow + 96 + cku * 8);
#pragma unroll
            for (int uu = 0; uu < 8; ++uu) {
                int u = cku * 8 + uu;
                const _Float16* pA = B1t + u * 1024;          // seg0 (s.s^T)
                const _Float16* pG = B1t + 32768 + u * 1024;  // seg1 (Gram)
                const _Float16* pV = B2t + u * 1024;          // y_v (W2+W3 folded)
                half8 bA0 = *(const half8*)(pA);
                half8 bA1 = *(const half8*)(pA + 512);
                half8 bG0 = *(const half8*)(pG);
                half8 bG1 = *(const half8*)(pG + 512);
                half8 bV0 = *(const half8*)(pV);
                half8 bV1 = *(const half8*)(pV + 512);
                _Float16 su = bcS[uu];
                _Float16 g0 = bcG0[uu], g1 = bcG1[uu], g2 = bcG2[uu];

                // ---- ys: s.s^T ----
                half8 af;
                af = sl_s[0] * su;
                acc_s = __builtin_amdgcn_mfma_f32_32x32x16_f16(af, bA0, acc_s, 0, 0, 0);
                af = sl_s[1] * su;
                acc_s = __builtin_amdgcn_mfma_f32_32x32x16_f16(af, bA1, acc_s, 0, 0, 0);
                // ---- ys: Gram(v) ----
                af = sl_v[0][0] * g0 + sl_v[0][1] * g1 + sl_v[0][2] * g2;
                acc_s = __builtin_amdgcn_mfma_f32_32x32x16_f16(af, bG0, acc_s, 0, 0, 0);
                af = sl_v[1][0] * g0 + sl_v[1][1] * g1 + sl_v[1][2] * g2;
                acc_s = __builtin_amdgcn_mfma_f32_32x32x16_f16(af, bG1, acc_s, 0, 0, 0);
                // ---- yv: s[u] v[v,kc], B2 shared across kc ----
#pragma unroll
                for (int kc = 0; kc < 3; ++kc) {
                    half8 af0 = sl_v[0][kc] * su;
                    acc_v[kc] = __builtin_amdgcn_mfma_f32_32x32x16_f16(af0, bV0, acc_v[kc], 0, 0, 0);
                    half8 af1 = sl_v[1][kc] * su;
                    acc_v[kc] = __builtin_amdgcn_mfma_f32_32x32x16_f16(af1, bV1, acc_v[kc], 0, 0, 0);
                }
            }
        }
    }

    // ---- epilogue: 32x32 C/D layout col(n)=lane&31, row=(reg&3)+8*(reg>>2)+4*q8 ----
    float* yg = y + (size_t)wg * (96 * 128);
    const int pb = wave * 32 + q8 * 4;
#pragma unroll
    for (int r = 0; r < 16; ++r) {
        int pos = pb + (r & 3) + 8 * (r >> 2);
        float* yp = yg + pos * 128;
        yp[mw] = acc_s[r];
        yp[32 + 3 * mw + 0] = acc_v[0][r];
        yp[32 + 3 * mw + 1] = acc_v[1][r];
        yp[32 + 3 * mw + 2] = acc_v[2][r];
    }
}

extern "C" void kernel_launch(void* const* d_in, const int* in_sizes, int n_in,
                              void* d_out, int out_size, void* d_ws, size_t ws_size,
                              hipStream_t stream) {
    const float* x  = (const float*)d_in[0];
    const float* Wa = (const float*)d_in[1];
    const float* Wb = (const float*)d_in[2];
    const float* Wc = (const float*)d_in[3];
    const float* Wd = (const float*)d_in[4];
    float* y = (float*)d_out;

    _Float16* B1s = (_Float16*)d_ws;           // 262144 half = 512 KB
    _Float16* B2s = B1s + 262144;              // 131072 half = 256 KB

    int nbatch = in_sizes[0] / 768;            // 16384
    int nwg = nbatch / 16;                     // 1024

    prep_kernel<<<(262144 + 131072) / 256, 256, 0, stream>>>(Wa, Wb, Wc, Wd, B1s, B2s);
    petp_main<<<nwg, 192, 0, stream>>>(x, B1s, B2s, y);
}

// Round 2
// 260.314 us; speedup vs baseline: 1.2451x; 1.2451x over previous
//
#include <hip/hip_runtime.h>

// PETP_Quadratic R5: R4 (32x32x16, lane-owns-position) + double-buffered
// LDS staging of B via global_load_lds.
//   - B table (768 KB) re-laid-out as Ball[t][u][slot][512], slot =
//     {A_kh0, A_kh1, G_kh0, G_kh1, V_kh0, V_kh1}; per (t,u) = 6 KB.
//   - Per chunk (2 u-steps = 12 KB): issue async DMA for chunk c+1,
//     consume chunk c from LDS (conflict-free ds_read_b128), vmcnt(0)+barrier.
//   - B now read from L2 once per BLOCK (393 MB total) instead of per wave
//     (2.4 GB), and load latency hides under MFMA/VALU of current chunk.
//   - y stores nontemporal: keep B resident in per-XCD L2.
// c-loop fully unrolled so all ext-vector indices are compile-time (no scratch).

typedef _Float16 half8  __attribute__((ext_vector_type(8)));
typedef float    f32x16 __attribute__((ext_vector_type(16)));

#define NORM 0.022097086912079608f   /* 1/(32*sqrt(2)) */
#define INV_SQRT3 0.5773502691896258f
#define STR 136                       /* feat row stride in halfwords (272B) */

// ---------------- prep: fragment-swizzled f16 weights, per-(t,u) interleave ----
// Ball[((t*32+u)*6 + slot)*512 + e], e = lane*8+j: lane n = lane&31, kq = lane>>5,
// kh = slot&1, k-channel v = kh*16 + kq*8 + j.
//   slot 0,1: NORM*W0[u][v][n]
//   slot 2,3: NORM*INV_SQRT3*W1[u][v][n]
//   slot 4,5: NORM*(W2[u][v][n] + W3[v][u][n])
__global__ void prep_kernel(const float* __restrict__ Wa, const float* __restrict__ Wb,
                            const float* __restrict__ Wc, const float* __restrict__ Wd,
                            _Float16* __restrict__ Ball) {
    const float* Ws[4] = {Wa, Wb, Wc, Wd};
    int idx = blockIdx.x * 256 + threadIdx.x;
    if (idx >= 393216) return;
    int e    = idx & 511;
    int frag = idx >> 9;          // 0..767
    int slot = frag % 6;
    int tu   = frag / 6;
    int u = tu & 31;
    int t = tu >> 5;
    int j = e & 7, lane = e >> 3;
    int n = lane & 31, kq = lane >> 5;
    int kh = slot & 1, seg = slot >> 1;
    int v = kh * 16 + kq * 8 + j;
    const float* W = Ws[t];
    float val;
    if (seg == 0)      val = NORM * W[u * 1024 + v * 32 + n];
    else if (seg == 1) val = NORM * INV_SQRT3 * W[32768 + u * 1024 + v * 32 + n];
    else               val = NORM * (W[65536 + u * 1024 + v * 32 + n] +
                                     W[98304 + v * 1024 + u * 32 + n]);
    Ball[idx] = (_Float16)val;
}

// async global->LDS, 16B per lane. LDS dest = wave-uniform base + lane*16 (linear).
__device__ __forceinline__ void gload_lds16(const _Float16* g, _Float16* l) {
    __builtin_amdgcn_global_load_lds(
        (const __attribute__((address_space(1))) unsigned int*)g,
        (__attribute__((address_space(3))) unsigned int*)l, 16, 0, 0);
}

// ---------------- main kernel ----------------
// WG = 192 thr (3 waves) owns 16 batches = 96 positions; wave owns 32 (one M-tile).
// feat[pos][ch] pos-major: ch 0..31 = s, 32+i*32+u = v-component i channel u.
__launch_bounds__(192, 3)
__global__ void petp_main(const float* __restrict__ x,
                          const _Float16* __restrict__ Ball,
                          float* __restrict__ y) {
    __shared__ _Float16 feat[96 * STR];   // 26,112 B
    __shared__ _Float16 Bst[2][6144];     // 2 x 12KB staging buffers

    const int tid  = threadIdx.x;
    const int wave = tid >> 6;
    const int lane = tid & 63;
    const int mw = lane & 31;   // A row (position in tile) AND C/D col n
    const int q8 = lane >> 5;   // k-half within a K=16 MFMA
    const int wvu = __builtin_amdgcn_readfirstlane(wave);

    f32x16 acc_s;
    f32x16 acc_v[3];
#pragma unroll
    for (int r = 0; r < 16; ++r) {
        acc_s[r] = 0.f; acc_v[0][r] = 0.f; acc_v[1][r] = 0.f; acc_v[2][r] = 0.f;
    }

    const int wg = blockIdx.x;
    const float* xg = x + (size_t)wg * (96 * 128);

#pragma unroll 1
    for (int t = 0; t < 4; ++t) {
        const _Float16* Bt = Ball + t * 98304;

        // ---- stage chunk 0 (u=0,1) into Bst[0]; latency hides under feat build ----
#pragma unroll
        for (int i = 0; i < 4; ++i) {
            int fi = wvu * 4 + i;
            gload_lds16(Bt + fi * 512 + lane * 8, &Bst[0][fi * 512]);
        }

        // ---- build variant-t features into pos-major LDS ----
        // (prev variant's final barrier guarantees old readers are done)
#pragma unroll 1
        for (int it = 0; it < 11; ++it) {
            int item = it * 192 + tid;        // 16 batches x 128 channels
            if (item < 2048) {
                int b = item >> 7;
                int c = item & 127;
                const float* bp = xg + b * 768 + c;
                float v00 = bp[0],   v01 = bp[128], v02 = bp[256];
                float v10 = bp[384], v11 = bp[512], v12 = bp[640];
                float rs0 = v00 + v01 + v02, rs1 = v10 + v11 + v12;
                float cs0 = v00 + v10, cs1 = v01 + v11, cs2 = v02 + v12;
                float tot = rs0 + rs1;
                float xv[6] = {v00, v01, v02, v10, v11, v12};
                float rs[2] = {rs0, rs1};
                float cs[3] = {cs0, cs1, cs2};
                int row;
                if (c < 32) row = c;
                else { int cc = c - 32; row = 32 + (cc % 3) * 32 + (cc / 3); }
                _Float16* fp = feat + row;
#pragma unroll
                for (int p6 = 0; p6 < 6; ++p6) {
                    int i = p6 / 3, j = p6 % 3;
                    float xvv = xv[p6];
                    float f;
                    if      (t == 0) f = xvv;
                    else if (t == 1) f = (rs[i] - xvv) * 0.5f;
                    else if (t == 2) f = cs[j] - xvv;
                    else             f = (tot - rs[i] - cs[j] + xvv) * 0.5f;
                    fp[(b * 6 + p6) * STR] = (_Float16)f;
                }
            }
        }
        asm volatile("s_waitcnt vmcnt(0)" ::: "memory");   // chunk 0 landed
        __syncthreads();                                   // + feat ready

        // ---- per-lane A-side: everything from my own position's row ----
        const _Float16* frow = feat + (wave * 32 + mw) * STR;
        half8 sl_s[2];       // k-slices of s (kh)
        half8 sl_v[2][3];    // k-slices of v (kh, component)
#pragma unroll
        for (int kh = 0; kh < 2; ++kh) {
            sl_s[kh] = *(const half8*)(frow + kh * 16 + q8 * 8);
#pragma unroll
            for (int i = 0; i < 3; ++i)
                sl_v[kh][i] = *(const half8*)(frow + 32 + i * 32 + kh * 16 + q8 * 8);
        }

        half8 bcS, bcG0, bcG1, bcG2;   // broadcast chunk: 8 u-values, register-resident

        // ---- 16 chunks x 2 u-steps, double-buffered ----
#pragma unroll
        for (int c = 0; c < 16; ++c) {
            if (c < 15) {   // issue DMA for chunk c+1 into the other buffer
#pragma unroll
                for (int i = 0; i < 4; ++i) {
                    int fi = wvu * 4 + i;
                    gload_lds16(Bt + ((c + 1) * 12 + fi) * 512 + lane * 8,
                                &Bst[(c + 1) & 1][fi * 512]);
                }
            }
            if ((c & 3) == 0) {
                const int cku = c >> 2;
                bcS  = *(const half8*)(frow + cku * 8);
                bcG0 = *(const half8*)(frow + 32 + cku * 8);
                bcG1 = *(const half8*)(frow + 64 + cku * 8);
                bcG2 = *(const half8*)(frow + 96 + cku * 8);
            }
            const _Float16* BstC = &Bst[c & 1][0];
#pragma unroll
            for (int ul = 0; ul < 2; ++ul) {
                const int uu = (c * 2 + ul) & 7;   // compile-time (loop unrolled)
                const _Float16* F = BstC + ul * 3072 + lane * 8;
                half8 bA0 = *(const half8*)(F);
                half8 bA1 = *(const half8*)(F + 512);
                half8 bG0 = *(const half8*)(F + 1024);
                half8 bG1 = *(const half8*)(F + 1536);
                half8 bV0 = *(const half8*)(F + 2048);
                half8 bV1 = *(const half8*)(F + 2560);
                _Float16 su = bcS[uu];
                _Float16 g0 = bcG0[uu], g1 = bcG1[uu], g2 = bcG2[uu];

                half8 af;
                // ---- ys: s.s^T ----
                af = sl_s[0] * su;
                acc_s = __builtin_amdgcn_mfma_f32_32x32x16_f16(af, bA0, acc_s, 0, 0, 0);
                af = sl_s[1] * su;
                acc_s = __builtin_amdgcn_mfma_f32_32x32x16_f16(af, bA1, acc_s, 0, 0, 0);
                // ---- ys: Gram(v) ----
                af = sl_v[0][0] * g0 + sl_v[0][1] * g1 + sl_v[0][2] * g2;
                acc_s = __builtin_amdgcn_mfma_f32_32x32x16_f16(af, bG0, acc_s, 0, 0, 0);
                af = sl_v[1][0] * g0 + sl_v[1][1] * g1 + sl_v[1][2] * g2;
                acc_s = __builtin_amdgcn_mfma_f32_32x32x16_f16(af, bG1, acc_s, 0, 0, 0);
                // ---- yv: s[u] v[v,kc], B2 shared across kc ----
#pragma unroll
                for (int kc = 0; kc < 3; ++kc) {
                    half8 af0 = sl_v[0][kc] * su;
                    acc_v[kc] = __builtin_amdgcn_mfma_f32_32x32x16_f16(af0, bV0, acc_v[kc], 0, 0, 0);
                    half8 af1 = sl_v[1][kc] * su;
                    acc_v[kc] = __builtin_amdgcn_mfma_f32_32x32x16_f16(af1, bV1, acc_v[kc], 0, 0, 0);
                }
            }
            // chunk c+1 landed (mine) + everyone done reading chunk c
            asm volatile("s_waitcnt vmcnt(0)" ::: "memory");
            __syncthreads();
        }
    }

    // ---- epilogue: 32x32 C/D layout col(n)=lane&31, row=(reg&3)+8*(reg>>2)+4*q8 ----
    // nontemporal: y is write-once streaming; keep B resident in L2.
    float* yg = y + (size_t)wg * (96 * 128);
    const int pb = wave * 32 + q8 * 4;
#pragma unroll
    for (int r = 0; r < 16; ++r) {
        int pos = pb + (r & 3) + 8 * (r >> 2);
        float* yp = yg + pos * 128;
        __builtin_nontemporal_store(acc_s[r], yp + mw);
        __builtin_nontemporal_store(acc_v[0][r], yp + 32 + 3 * mw + 0);
        __builtin_nontemporal_store(acc_v[1][r], yp + 32 + 3 * mw + 1);
        __builtin_nontemporal_store(acc_v[2][r], yp + 32 + 3 * mw + 2);
    }
}

extern "C" void kernel_launch(void* const* d_in, const int* in_sizes, int n_in,
                              void* d_out, int out_size, void* d_ws, size_t ws_size,
                              hipStream_t stream) {
    const float* x  = (const float*)d_in[0];
    const float* Wa = (const float*)d_in[1];
    const float* Wb = (const float*)d_in[2];
    const float* Wc = (const float*)d_in[3];
    const float* Wd = (const float*)d_in[4];
    float* y = (float*)d_out;

    _Float16* Ball = (_Float16*)d_ws;          // 393216 half = 768 KB

    int nbatch = in_sizes[0] / 768;            // 16384
    int nwg = nbatch / 16;                     // 1024

    prep_kernel<<<1536, 256, 0, stream>>>(Wa, Wb, Wc, Wd, Ball);
    petp_main<<<nwg, 192, 0, stream>>>(x, Ball, y);
}